// Round 12
// baseline (306.482 us; speedup 1.0000x reference)
//
#include <hip/hip_runtime.h>

#define DF 256
#define HID 16
#define WB 512          // edge slices == fused grid size
#define NBLK 512
#define PBITS 8         // partition = 256 nodes
#define PMAX 512
#define PPAD 512        // padded stride for cntS[w][p]

// ---------------- grid barrier (agent-scope release/acquire, spin-capped) ----------------
__device__ __forceinline__ void gbar(unsigned* cnt, unsigned target) {
    __syncthreads();
    if (threadIdx.x == 0) {
        __hip_atomic_fetch_add(cnt, 1u, __ATOMIC_RELEASE, __HIP_MEMORY_SCOPE_AGENT);
        unsigned it = 0;
        while (__hip_atomic_load(cnt, __ATOMIC_ACQUIRE, __HIP_MEMORY_SCOPE_AGENT) < target
               && ++it < (1u << 26))
            __builtin_amdgcn_s_sleep(2);
    }
    __syncthreads();
}

// ---------- K1: wave-specialized hist (waves 0-1) || sval (waves 2-7) ----------
__global__ void __launch_bounds__(512)
hist_sval_kernel(const float* __restrict__ x, const int* __restrict__ dst,
                 const float* __restrict__ Wm, const float* __restrict__ W_fc,
                 unsigned* __restrict__ cntS, float* __restrict__ sv,
                 int N, int E, int P, int Epw) {
    __shared__ unsigned h[PMAX];
    for (int i = threadIdx.x; i < P; i += 512) h[i] = 0u;
    __syncthreads();
    const int w = blockIdx.x, tid = threadIdx.x;
    if (tid < 128) {   // hist waves (wave-uniform branch)
        const size_t e0 = (size_t)w * Epw;
        long rem = (long)E - (long)e0;
        int m = rem < 0 ? 0 : (rem > Epw ? Epw : (int)rem);
        const int m4 = m >> 2;
        const int4* d4 = reinterpret_cast<const int4*>(dst + e0);
        for (int iv = tid; iv < m4; iv += 128) {
            int4 d = d4[iv];
            atomicAdd(&h[((unsigned)d.x) >> PBITS], 1u);
            atomicAdd(&h[((unsigned)d.y) >> PBITS], 1u);
            atomicAdd(&h[((unsigned)d.z) >> PBITS], 1u);
            atomicAdd(&h[((unsigned)d.w) >> PBITS], 1u);
        }
        for (int i = (m4 << 2) + tid; i < m; i += 128)
            atomicAdd(&h[((unsigned)dst[e0 + i]) >> PBITS], 1u);
    } else {           // sval waves: 6 per block, 3072 total, x4 row batching
        const int lane = tid & 63, swid = (tid >> 6) - 2;
        const int gw = w * 6 + swid;
        const int GW = WB * 6;   // 3072
        float a0 = 0.f, a1 = 0.f, a2 = 0.f, a3 = 0.f;
        const float* wrow = Wm + (size_t)(lane * 4) * HID;
#pragma unroll
        for (int k = 0; k < HID; ++k) {
            float f = W_fc[k];
            a0 += wrow[k] * f;
            a1 += wrow[HID + k] * f;
            a2 += wrow[2 * HID + k] * f;
            a3 += wrow[3 * HID + k] * f;
        }
        for (int r0 = gw; r0 < N; r0 += 4 * GW) {
            int r1 = r0 + GW, r2 = r0 + 2 * GW, r3 = r0 + 3 * GW;
            float4 v0, v1, v2, v3;
            v0 = reinterpret_cast<const float4*>(x + (size_t)r0 * DF)[lane];
            if (r1 < N) v1 = reinterpret_cast<const float4*>(x + (size_t)r1 * DF)[lane];
            if (r2 < N) v2 = reinterpret_cast<const float4*>(x + (size_t)r2 * DF)[lane];
            if (r3 < N) v3 = reinterpret_cast<const float4*>(x + (size_t)r3 * DF)[lane];
            float s0 = v0.x * a0 + v0.y * a1 + v0.z * a2 + v0.w * a3;
            float s1 = (r1 < N) ? (v1.x * a0 + v1.y * a1 + v1.z * a2 + v1.w * a3) : 0.f;
            float s2 = (r2 < N) ? (v2.x * a0 + v2.y * a1 + v2.z * a2 + v2.w * a3) : 0.f;
            float s3 = (r3 < N) ? (v3.x * a0 + v3.y * a1 + v3.z * a2 + v3.w * a3) : 0.f;
#pragma unroll
            for (int off = 32; off > 0; off >>= 1) {
                s0 += __shfl_xor(s0, off, 64);
                s1 += __shfl_xor(s1, off, 64);
                s2 += __shfl_xor(s2, off, 64);
                s3 += __shfl_xor(s3, off, 64);
            }
            if (lane == 0) {
                sv[r0] = s0;
                if (r1 < N) sv[r1] = s1;
                if (r2 < N) sv[r2] = s2;
                if (r3 < N) sv[r3] = s3;
            }
        }
    }
    __syncthreads();
    for (int p = threadIdx.x; p < P; p += 512) cntS[(size_t)w * PPAD + p] = h[p];
}

// ---------- K2: fused scan | scatter | deg | reduce (3 grid barriers) ----------
__global__ void __launch_bounds__(512, 4)
fused_kernel(const int* __restrict__ src, const int* __restrict__ dst,
             unsigned* __restrict__ cntS, unsigned* __restrict__ rowTotal,
             unsigned* __restrict__ sorted, const float* __restrict__ sv,
             float* __restrict__ dinv, float* __restrict__ tval,
             const float* __restrict__ b_conv, const float* __restrict__ W_fc,
             const float* __restrict__ b_fc, float* __restrict__ out,
             unsigned* __restrict__ bars, int N, int E, int P, int Epw, unsigned cap) {
    __shared__ unsigned wsum[8];
    __shared__ unsigned cur[PMAX];
    __shared__ unsigned dc[256];
    __shared__ float facc[256];
    const int t = threadIdx.x;

    // ---- P1: per-partition exclusive scan across 512 slices; absolute base += p*cap ----
    if (blockIdx.x < (unsigned)P) {
        const int p = blockIdx.x;
        const int lane = t & 63, wv = t >> 6;
        unsigned v = cntS[(size_t)t * PPAD + p];
        unsigned xi = v;
#pragma unroll
        for (int off = 1; off < 64; off <<= 1) {
            unsigned u = __shfl_up(xi, off, 64);
            if (lane >= off) xi += u;
        }
        if (lane == 63) wsum[wv] = xi;
        __syncthreads();
        if (t < 8) {
            unsigned u = wsum[t];
#pragma unroll
            for (int off = 1; off < 8; off <<= 1) {
                unsigned uu = __shfl_up(u, off, 64);
                if (t >= off) u += uu;
            }
            wsum[t] = u;
        }
        __syncthreads();
        unsigned base = wv ? wsum[wv - 1] : 0u;
        cntS[(size_t)t * PPAD + p] = xi - v + base + (unsigned)p * cap;
        if (t == 0) rowTotal[p] = wsum[7];
    }
    gbar(&bars[0], NBLK);

    // ---- P2: scatter into fixed-cap partition regions ----
    {
        const int w = blockIdx.x;
        for (int p = t; p < P; p += 512) cur[p] = cntS[(size_t)w * PPAD + p];
        __syncthreads();
        const size_t e0 = (size_t)w * Epw;
        long rem = (long)E - (long)e0;
        int m = rem < 0 ? 0 : (rem > Epw ? Epw : (int)rem);
        const int m4 = m >> 2;
        const int4* s4 = reinterpret_cast<const int4*>(src + e0);
        const int4* d4 = reinterpret_cast<const int4*>(dst + e0);
        for (int iv = t; iv < m4; iv += 512) {
            int4 s = s4[iv];
            int4 d = d4[iv];
            unsigned t0 = atomicAdd(&cur[((unsigned)d.x) >> PBITS], 1u);
            unsigned t1 = atomicAdd(&cur[((unsigned)d.y) >> PBITS], 1u);
            unsigned t2 = atomicAdd(&cur[((unsigned)d.z) >> PBITS], 1u);
            unsigned t3 = atomicAdd(&cur[((unsigned)d.w) >> PBITS], 1u);
            sorted[t0] = ((unsigned)s.x << PBITS) | ((unsigned)d.x & 255u);
            sorted[t1] = ((unsigned)s.y << PBITS) | ((unsigned)d.y & 255u);
            sorted[t2] = ((unsigned)s.z << PBITS) | ((unsigned)d.z & 255u);
            sorted[t3] = ((unsigned)s.w << PBITS) | ((unsigned)d.w & 255u);
        }
        for (int i = (m4 << 2) + t; i < m; i += 512) {
            unsigned s = (unsigned)src[e0 + i], d = (unsigned)dst[e0 + i];
            unsigned slot = atomicAdd(&cur[d >> PBITS], 1u);
            sorted[slot] = (s << PBITS) | (d & 255u);
        }
    }
    gbar(&bars[1], NBLK);

    // ---- P3: degree walk -> dinv, tval ----
    if (blockIdx.x < (unsigned)P) {
        const int p = blockIdx.x;
        if (t < 256) dc[t] = 0u;
        __syncthreads();
        const unsigned cnt = rowTotal[p];
        const unsigned b0 = (unsigned)p * cap;
        const unsigned nv = cnt >> 2;
        const uint4* v4 = reinterpret_cast<const uint4*>(sorted + b0);
        for (unsigned iv = t; iv < nv; iv += 512) {
            uint4 v = v4[iv];
            atomicAdd(&dc[v.x & 255u], 1u); atomicAdd(&dc[v.y & 255u], 1u);
            atomicAdd(&dc[v.z & 255u], 1u); atomicAdd(&dc[v.w & 255u], 1u);
        }
        for (unsigned j = (nv << 2) + t; j < cnt; j += 512)
            atomicAdd(&dc[sorted[b0 + j] & 255u], 1u);
        __syncthreads();
        if (t < 256) {
            int i = (p << PBITS) + t;
            if (i < N) {
                float deg = 1.0f + (float)dc[t];
                float di = rsqrtf(deg);
                dinv[i] = di;
                tval[i] = sv[i] * di;
            }
        }
    }
    gbar(&bars[2], NBLK);

    // ---- P4: value walk -> out ----
    if (blockIdx.x < (unsigned)P) {
        const int p = blockIdx.x;
        if (t < 256) facc[t] = 0.f;
        __syncthreads();
        const unsigned cnt = rowTotal[p];
        const unsigned b0 = (unsigned)p * cap;
        const unsigned nv = cnt >> 2;
        const uint4* v4 = reinterpret_cast<const uint4*>(sorted + b0);
        for (unsigned iv = t; iv < nv; iv += 512) {
            uint4 v = v4[iv];
            float f0 = tval[v.x >> PBITS], f1 = tval[v.y >> PBITS];
            float f2 = tval[v.z >> PBITS], f3 = tval[v.w >> PBITS];
            atomicAdd(&facc[v.x & 255u], f0); atomicAdd(&facc[v.y & 255u], f1);
            atomicAdd(&facc[v.z & 255u], f2); atomicAdd(&facc[v.w & 255u], f3);
        }
        for (unsigned j = (nv << 2) + t; j < cnt; j += 512) {
            unsigned e = sorted[b0 + j];
            atomicAdd(&facc[e & 255u], tval[e >> PBITS]);
        }
        __syncthreads();
        if (t < 256) {
            int i = (p << PBITS) + t;
            if (i < N) {
                float c = 0.f;
#pragma unroll
                for (int k = 0; k < HID; ++k) c += b_conv[k] * W_fc[k];
                float di = dinv[i];
                out[i] = di * (tval[i] + facc[t]) + c + b_fc[0];
            }
        }
    }
}

// ---------- split-path kernels (r11 proven, used when co-residency not guaranteed) ----------
__global__ void __launch_bounds__(WB)
rowscan_kernel(unsigned* __restrict__ cntS, unsigned* __restrict__ rowTotal, unsigned cap) {
    __shared__ unsigned wsum[8];
    const int p = blockIdx.x, t = threadIdx.x;
    const int lane = t & 63, wv = t >> 6;
    unsigned v = cntS[(size_t)t * PPAD + p];
    unsigned xi = v;
#pragma unroll
    for (int off = 1; off < 64; off <<= 1) {
        unsigned u = __shfl_up(xi, off, 64);
        if (lane >= off) xi += u;
    }
    if (lane == 63) wsum[wv] = xi;
    __syncthreads();
    if (t < 8) {
        unsigned u = wsum[t];
#pragma unroll
        for (int off = 1; off < 8; off <<= 1) {
            unsigned uu = __shfl_up(u, off, 64);
            if (t >= off) u += uu;
        }
        wsum[t] = u;
    }
    __syncthreads();
    unsigned base = wv ? wsum[wv - 1] : 0u;
    cntS[(size_t)t * PPAD + p] = xi - v + base + (unsigned)p * cap;
    if (t == 0) rowTotal[p] = wsum[7];
}
__global__ void __launch_bounds__(512)
binscatter_kernel(const int* __restrict__ src, const int* __restrict__ dst,
                  const unsigned* __restrict__ cntS, unsigned* __restrict__ sorted,
                  int P, int E, int Epw) {
    __shared__ unsigned cur[PMAX];
    const int w = blockIdx.x;
    for (int p = threadIdx.x; p < P; p += 512) cur[p] = cntS[(size_t)w * PPAD + p];
    __syncthreads();
    const size_t e0 = (size_t)w * Epw;
    long rem = (long)E - (long)e0;
    int m = rem < 0 ? 0 : (rem > Epw ? Epw : (int)rem);
    const int m4 = m >> 2;
    const int4* s4 = reinterpret_cast<const int4*>(src + e0);
    const int4* d4 = reinterpret_cast<const int4*>(dst + e0);
    for (int iv = threadIdx.x; iv < m4; iv += 512) {
        int4 s = s4[iv];
        int4 d = d4[iv];
        unsigned t0 = atomicAdd(&cur[((unsigned)d.x) >> PBITS], 1u);
        unsigned t1 = atomicAdd(&cur[((unsigned)d.y) >> PBITS], 1u);
        unsigned t2 = atomicAdd(&cur[((unsigned)d.z) >> PBITS], 1u);
        unsigned t3 = atomicAdd(&cur[((unsigned)d.w) >> PBITS], 1u);
        sorted[t0] = ((unsigned)s.x << PBITS) | ((unsigned)d.x & 255u);
        sorted[t1] = ((unsigned)s.y << PBITS) | ((unsigned)d.y & 255u);
        sorted[t2] = ((unsigned)s.z << PBITS) | ((unsigned)d.z & 255u);
        sorted[t3] = ((unsigned)s.w << PBITS) | ((unsigned)d.w & 255u);
    }
    for (int i = (m4 << 2) + threadIdx.x; i < m; i += 512) {
        unsigned s = (unsigned)src[e0 + i], d = (unsigned)dst[e0 + i];
        unsigned slot = atomicAdd(&cur[d >> PBITS], 1u);
        sorted[slot] = (s << PBITS) | (d & 255u);
    }
}
__global__ void __launch_bounds__(1024)
degfin_kernel(const unsigned* __restrict__ sorted, const unsigned* __restrict__ rowTotal,
              const float* __restrict__ sv, float* __restrict__ dinv,
              float* __restrict__ tval, int N, unsigned cap) {
    __shared__ unsigned dc[256];
    const int p = blockIdx.x, t = threadIdx.x;
    if (t < 256) dc[t] = 0u;
    __syncthreads();
    const unsigned cnt = rowTotal[p];
    const unsigned b0 = (unsigned)p * cap;
    const unsigned nv = cnt >> 2;
    const uint4* v4 = reinterpret_cast<const uint4*>(sorted + b0);
    for (unsigned iv = t; iv < nv; iv += 1024) {
        uint4 v = v4[iv];
        atomicAdd(&dc[v.x & 255u], 1u); atomicAdd(&dc[v.y & 255u], 1u);
        atomicAdd(&dc[v.z & 255u], 1u); atomicAdd(&dc[v.w & 255u], 1u);
    }
    for (unsigned j = (nv << 2) + t; j < cnt; j += 1024)
        atomicAdd(&dc[sorted[b0 + j] & 255u], 1u);
    __syncthreads();
    if (t < 256) {
        int i = (p << PBITS) + t;
        if (i < N) {
            float deg = 1.0f + (float)dc[t];
            float di = rsqrtf(deg);
            dinv[i] = di;
            tval[i] = sv[i] * di;
        }
    }
}
__global__ void __launch_bounds__(1024)
reduce_kernel(const unsigned* __restrict__ sorted, const unsigned* __restrict__ rowTotal,
              const float* __restrict__ tval, const float* __restrict__ dinv,
              const float* __restrict__ b_conv, const float* __restrict__ W_fc,
              const float* __restrict__ b_fc, float* __restrict__ out, int N, unsigned cap) {
    __shared__ float facc[256];
    const int p = blockIdx.x, t = threadIdx.x;
    if (t < 256) facc[t] = 0.f;
    __syncthreads();
    const unsigned cnt = rowTotal[p];
    const unsigned b0 = (unsigned)p * cap;
    const unsigned nv = cnt >> 2;
    const uint4* v4 = reinterpret_cast<const uint4*>(sorted + b0);
    for (unsigned iv = t; iv < nv; iv += 1024) {
        uint4 v = v4[iv];
        float f0 = tval[v.x >> PBITS], f1 = tval[v.y >> PBITS];
        float f2 = tval[v.z >> PBITS], f3 = tval[v.w >> PBITS];
        atomicAdd(&facc[v.x & 255u], f0); atomicAdd(&facc[v.y & 255u], f1);
        atomicAdd(&facc[v.z & 255u], f2); atomicAdd(&facc[v.w & 255u], f3);
    }
    for (unsigned j = (nv << 2) + t; j < cnt; j += 1024) {
        unsigned e = sorted[b0 + j];
        atomicAdd(&facc[e & 255u], tval[e >> PBITS]);
    }
    __syncthreads();
    if (t < 256) {
        int i = (p << PBITS) + t;
        if (i < N) {
            float c = 0.f;
#pragma unroll
            for (int k = 0; k < HID; ++k) c += b_conv[k] * W_fc[k];
            float di = dinv[i];
            out[i] = di * (tval[i] + facc[t]) + c + b_fc[0];
        }
    }
}

extern "C" void kernel_launch(void* const* d_in, const int* in_sizes, int n_in,
                              void* d_out, int out_size, void* d_ws, size_t ws_size,
                              hipStream_t stream) {
    const float* x      = (const float*)d_in[0];
    const int*   ei     = (const int*)d_in[1];
    const float* Wm     = (const float*)d_in[2];
    const float* b_conv = (const float*)d_in[3];
    const float* W_fc   = (const float*)d_in[4];
    const float* b_fc   = (const float*)d_in[5];
    float* out = (float*)d_out;

    const int N = in_sizes[0] / DF;   // 100000
    const int E = in_sizes[1] / 2;    // 3200000
    const int* src = ei;
    const int* dst = ei + E;

    const int P   = (N + 255) >> PBITS;                 // 391
    const int Epw = (((E + WB - 1) / WB) + 3) & ~3;     // 6252, 16B-aligned slices
    const unsigned avg = (unsigned)((E + P - 1) / P);
    const unsigned cap = ((4u * avg) + 4095u) & ~4095u; // ~36864, 16B-aligned

    char* ws = (char*)d_ws;
    unsigned* bars = (unsigned*)ws;                         // 16 u32
    float* sv   = (float*)(ws + 64);                        // N
    float* dinv = sv + N;                                   // N
    float* tval = dinv + N;                                 // N
    unsigned* cntS     = (unsigned*)(tval + N);             // WB*PPAD
    unsigned* rowTotal = cntS + (size_t)WB * PPAD;          // 512
    unsigned* sorted   = rowTotal + 512;                    // P*cap

    const size_t need = 64 + ((size_t)3 * N + (size_t)WB * PPAD + 512 + (size_t)P * cap) * 4;
    const bool shape_ok = (P >= 1 && P <= PMAX && N <= (1 << 23) && ws_size >= need);

    int maxBlocksPerCU = 0, numCU = 0;
    bool occ_ok = false;
    if (shape_ok &&
        hipOccupancyMaxActiveBlocksPerMultiprocessor(&maxBlocksPerCU, fused_kernel, 512, 0)
            == hipSuccess &&
        hipDeviceGetAttribute(&numCU, hipDeviceAttributeMultiprocessorCount, 0) == hipSuccess)
        occ_ok = ((long)maxBlocksPerCU * numCU >= NBLK);

    if (shape_ok && occ_ok) {
        hipMemsetAsync(bars, 0, 64, stream);
        hist_sval_kernel<<<WB, 512, 0, stream>>>(x, dst, Wm, W_fc, cntS, sv, N, E, P, Epw);
        fused_kernel<<<NBLK, 512, 0, stream>>>(src, dst, cntS, rowTotal, sorted, sv,
                                               dinv, tval, b_conv, W_fc, b_fc, out, bars,
                                               N, E, P, Epw, cap);
    } else if (shape_ok) {
        hist_sval_kernel<<<WB, 512, 0, stream>>>(x, dst, Wm, W_fc, cntS, sv, N, E, P, Epw);
        rowscan_kernel<<<P, WB, 0, stream>>>(cntS, rowTotal, cap);
        binscatter_kernel<<<WB, 512, 0, stream>>>(src, dst, cntS, sorted, P, E, Epw);
        degfin_kernel<<<P, 1024, 0, stream>>>(sorted, rowTotal, sv, dinv, tval, N, cap);
        reduce_kernel<<<P, 1024, 0, stream>>>(sorted, rowTotal, tval, dinv,
                                              b_conv, W_fc, b_fc, out, N, cap);
    }
}

// Round 13
// 81.769 us; speedup vs baseline: 3.7481x; 3.7481x over previous
//
#include <hip/hip_runtime.h>

#define DF 256
#define HID 16
#define WB 512          // edge slices (= hist/scatter grid)
#define PBITS 8         // partition = 256 nodes
#define PMAX 512        // max partitions
#define PPAD 512        // padded partition stride for cntS[w][p]

// ---------- K1: wave-specialized — hist on waves 0-1 || sval on waves 2-7 ----------
__global__ void __launch_bounds__(512)
hist_sval_kernel(const float* __restrict__ x, const int* __restrict__ dst,
                 const float* __restrict__ Wm, const float* __restrict__ W_fc,
                 unsigned* __restrict__ cntS, float* __restrict__ sv,
                 int N, int E, int P, int Epw) {
    __shared__ unsigned h[PMAX];
    for (int i = threadIdx.x; i < P; i += 512) h[i] = 0u;
    __syncthreads();
    const int w = blockIdx.x, tid = threadIdx.x;
    if (tid < 128) {   // hist waves (wave-uniform branch)
        const size_t e0 = (size_t)w * Epw;   // Epw % 4 == 0 -> 16B aligned
        long rem = (long)E - (long)e0;
        int m = rem < 0 ? 0 : (rem > Epw ? Epw : (int)rem);
        const int m4 = m >> 2;
        const int4* d4 = reinterpret_cast<const int4*>(dst + e0);
        for (int iv = tid; iv < m4; iv += 128) {
            int4 d = d4[iv];
            atomicAdd(&h[((unsigned)d.x) >> PBITS], 1u);
            atomicAdd(&h[((unsigned)d.y) >> PBITS], 1u);
            atomicAdd(&h[((unsigned)d.z) >> PBITS], 1u);
            atomicAdd(&h[((unsigned)d.w) >> PBITS], 1u);
        }
        for (int i = (m4 << 2) + tid; i < m; i += 128)
            atomicAdd(&h[((unsigned)dst[e0 + i]) >> PBITS], 1u);
    } else {           // sval waves: 6 per block, 3072 total, x4 row batching
        const int lane = tid & 63, swid = (tid >> 6) - 2;
        const int gw = w * 6 + swid;
        const int GW = WB * 6;   // 3072
        float a0 = 0.f, a1 = 0.f, a2 = 0.f, a3 = 0.f;
        const float* wrow = Wm + (size_t)(lane * 4) * HID;
#pragma unroll
        for (int k = 0; k < HID; ++k) {
            float f = W_fc[k];
            a0 += wrow[k] * f;
            a1 += wrow[HID + k] * f;
            a2 += wrow[2 * HID + k] * f;
            a3 += wrow[3 * HID + k] * f;
        }
        for (int r0 = gw; r0 < N; r0 += 4 * GW) {
            int r1 = r0 + GW, r2 = r0 + 2 * GW, r3 = r0 + 3 * GW;
            float4 v0, v1, v2, v3;
            v0 = reinterpret_cast<const float4*>(x + (size_t)r0 * DF)[lane];
            if (r1 < N) v1 = reinterpret_cast<const float4*>(x + (size_t)r1 * DF)[lane];
            if (r2 < N) v2 = reinterpret_cast<const float4*>(x + (size_t)r2 * DF)[lane];
            if (r3 < N) v3 = reinterpret_cast<const float4*>(x + (size_t)r3 * DF)[lane];
            float s0 = v0.x * a0 + v0.y * a1 + v0.z * a2 + v0.w * a3;
            float s1 = (r1 < N) ? (v1.x * a0 + v1.y * a1 + v1.z * a2 + v1.w * a3) : 0.f;
            float s2 = (r2 < N) ? (v2.x * a0 + v2.y * a1 + v2.z * a2 + v2.w * a3) : 0.f;
            float s3 = (r3 < N) ? (v3.x * a0 + v3.y * a1 + v3.z * a2 + v3.w * a3) : 0.f;
#pragma unroll
            for (int off = 32; off > 0; off >>= 1) {
                s0 += __shfl_xor(s0, off, 64);
                s1 += __shfl_xor(s1, off, 64);
                s2 += __shfl_xor(s2, off, 64);
                s3 += __shfl_xor(s3, off, 64);
            }
            if (lane == 0) {
                sv[r0] = s0;
                if (r1 < N) sv[r1] = s1;
                if (r2 < N) sv[r2] = s2;
                if (r3 < N) sv[r3] = s3;
            }
        }
    }
    __syncthreads();
    for (int p = threadIdx.x; p < P; p += 512) cntS[(size_t)w * PPAD + p] = h[p];
}

// ---------- K2: per-partition scan across slices; writes absolute base (incl. p*cap) ----------
__global__ void __launch_bounds__(WB)
rowscan_kernel(unsigned* __restrict__ cntS, unsigned* __restrict__ rowTotal, unsigned cap) {
    __shared__ unsigned wsum[8];
    const int p = blockIdx.x, t = threadIdx.x;
    const int lane = t & 63, wv = t >> 6;
    unsigned v = cntS[(size_t)t * PPAD + p];
    unsigned xi = v;
#pragma unroll
    for (int off = 1; off < 64; off <<= 1) {
        unsigned u = __shfl_up(xi, off, 64);
        if (lane >= off) xi += u;
    }
    if (lane == 63) wsum[wv] = xi;
    __syncthreads();
    if (t < 8) {
        unsigned u = wsum[t];
#pragma unroll
        for (int off = 1; off < 8; off <<= 1) {
            unsigned uu = __shfl_up(u, off, 64);
            if (t >= off) u += uu;
        }
        wsum[t] = u;
    }
    __syncthreads();
    unsigned base = wv ? wsum[wv - 1] : 0u;
    cntS[(size_t)t * PPAD + p] = xi - v + base + (unsigned)p * cap;  // absolute slot base
    if (t == 0) rowTotal[p] = wsum[7];
}

// ---------- K3: scatter into fixed-cap partition regions (int4 loads) ----------
__global__ void __launch_bounds__(512)
binscatter_kernel(const int* __restrict__ src, const int* __restrict__ dst,
                  const unsigned* __restrict__ cntS, unsigned* __restrict__ sorted,
                  int P, int E, int Epw) {
    __shared__ unsigned cur[PMAX];
    const int w = blockIdx.x;
    for (int p = threadIdx.x; p < P; p += 512)
        cur[p] = cntS[(size_t)w * PPAD + p];   // coalesced
    __syncthreads();
    const size_t e0 = (size_t)w * Epw;
    long rem = (long)E - (long)e0;
    int m = rem < 0 ? 0 : (rem > Epw ? Epw : (int)rem);
    const int m4 = m >> 2;
    const int4* s4 = reinterpret_cast<const int4*>(src + e0);
    const int4* d4 = reinterpret_cast<const int4*>(dst + e0);
    for (int iv = threadIdx.x; iv < m4; iv += 512) {
        int4 s = s4[iv];
        int4 d = d4[iv];
        unsigned t0 = atomicAdd(&cur[((unsigned)d.x) >> PBITS], 1u);
        unsigned t1 = atomicAdd(&cur[((unsigned)d.y) >> PBITS], 1u);
        unsigned t2 = atomicAdd(&cur[((unsigned)d.z) >> PBITS], 1u);
        unsigned t3 = atomicAdd(&cur[((unsigned)d.w) >> PBITS], 1u);
        sorted[t0] = ((unsigned)s.x << PBITS) | ((unsigned)d.x & 255u);
        sorted[t1] = ((unsigned)s.y << PBITS) | ((unsigned)d.y & 255u);
        sorted[t2] = ((unsigned)s.z << PBITS) | ((unsigned)d.z & 255u);
        sorted[t3] = ((unsigned)s.w << PBITS) | ((unsigned)d.w & 255u);
    }
    for (int i = (m4 << 2) + threadIdx.x; i < m; i += 512) {
        unsigned s = (unsigned)src[e0 + i], d = (unsigned)dst[e0 + i];
        unsigned slot = atomicAdd(&cur[d >> PBITS], 1u);
        sorted[slot] = (s << PBITS) | (d & 255u);
    }
}

// ---------- K4: degree walk (uint4) -> dinv, tval ----------
__global__ void __launch_bounds__(1024)
degfin_kernel(const unsigned* __restrict__ sorted, const unsigned* __restrict__ rowTotal,
              const float* __restrict__ sv, float* __restrict__ dinv,
              float* __restrict__ tval, int N, unsigned cap) {
    __shared__ unsigned dc[256];
    const int p = blockIdx.x, t = threadIdx.x;
    if (t < 256) dc[t] = 0u;
    __syncthreads();
    const unsigned cnt = rowTotal[p];
    const unsigned b0 = (unsigned)p * cap;
    const unsigned nv = cnt >> 2;
    const uint4* v4 = reinterpret_cast<const uint4*>(sorted + b0);
    for (unsigned iv = t; iv < nv; iv += 1024) {
        uint4 v = v4[iv];
        atomicAdd(&dc[v.x & 255u], 1u); atomicAdd(&dc[v.y & 255u], 1u);
        atomicAdd(&dc[v.z & 255u], 1u); atomicAdd(&dc[v.w & 255u], 1u);
    }
    for (unsigned j = (nv << 2) + t; j < cnt; j += 1024)
        atomicAdd(&dc[sorted[b0 + j] & 255u], 1u);
    __syncthreads();
    if (t < 256) {
        int i = (p << PBITS) + t;
        if (i < N) {
            float deg = 1.0f + (float)dc[t];
            float di = rsqrtf(deg);
            dinv[i] = di;
            tval[i] = sv[i] * di;
        }
    }
}

// ---------- K5: value walk (uint4) -> out = di*(tval + acc) + c ----------
__global__ void __launch_bounds__(1024)
reduce_kernel(const unsigned* __restrict__ sorted, const unsigned* __restrict__ rowTotal,
              const float* __restrict__ tval, const float* __restrict__ dinv,
              const float* __restrict__ b_conv, const float* __restrict__ W_fc,
              const float* __restrict__ b_fc, float* __restrict__ out, int N, unsigned cap) {
    __shared__ float facc[256];
    const int p = blockIdx.x, t = threadIdx.x;
    if (t < 256) facc[t] = 0.f;
    __syncthreads();
    const unsigned cnt = rowTotal[p];
    const unsigned b0 = (unsigned)p * cap;
    const unsigned nv = cnt >> 2;
    const uint4* v4 = reinterpret_cast<const uint4*>(sorted + b0);
    for (unsigned iv = t; iv < nv; iv += 1024) {
        uint4 v = v4[iv];
        float f0 = tval[v.x >> PBITS], f1 = tval[v.y >> PBITS];
        float f2 = tval[v.z >> PBITS], f3 = tval[v.w >> PBITS];
        atomicAdd(&facc[v.x & 255u], f0); atomicAdd(&facc[v.y & 255u], f1);
        atomicAdd(&facc[v.z & 255u], f2); atomicAdd(&facc[v.w & 255u], f3);
    }
    for (unsigned j = (nv << 2) + t; j < cnt; j += 1024) {
        unsigned e = sorted[b0 + j];
        atomicAdd(&facc[e & 255u], tval[e >> PBITS]);
    }
    __syncthreads();
    if (t < 256) {
        int i = (p << PBITS) + t;
        if (i < N) {
            float c = 0.f;
#pragma unroll
            for (int k = 0; k < HID; ++k) c += b_conv[k] * W_fc[k];
            float di = dinv[i];
            out[i] = di * (tval[i] + facc[t]) + c + b_fc[0];
        }
    }
}

// ---------- fallback: proven global-atomic path ----------
__global__ void fb_sval(const float* __restrict__ x, const float* __restrict__ Wm,
                        const float* __restrict__ W_fc, float* __restrict__ sv, int N) {
    __shared__ float wl[DF];
    int k = threadIdx.x;
    float a = 0.f;
#pragma unroll
    for (int j = 0; j < HID; ++j) a += Wm[k * HID + j] * W_fc[j];
    wl[k] = a;
    __syncthreads();
    int lane = threadIdx.x & 63, wid = threadIdx.x >> 6;
    float4 wv = reinterpret_cast<const float4*>(wl)[lane];
    for (int row = blockIdx.x * 4 + wid; row < N; row += gridDim.x * 4) {
        float4 xv = reinterpret_cast<const float4*>(x + (size_t)row * DF)[lane];
        float acc = xv.x * wv.x + xv.y * wv.y + xv.z * wv.z + xv.w * wv.w;
#pragma unroll
        for (int off = 32; off > 0; off >>= 1) acc += __shfl_xor(acc, off, 64);
        if (lane == 0) sv[row] = acc;
    }
}
__global__ void fb_count(const int* __restrict__ dst, unsigned* __restrict__ cnt, int E) {
    int stride = gridDim.x * blockDim.x;
    for (int e = blockIdx.x * blockDim.x + threadIdx.x; e < E; e += stride)
        atomicAdd(&cnt[dst[e]], 1u);
}
__global__ void fb_node(const unsigned* __restrict__ cnt, const float* __restrict__ sv,
                        const float* __restrict__ b_conv, const float* __restrict__ W_fc,
                        const float* __restrict__ b_fc, float* __restrict__ dinv,
                        float* __restrict__ tval, float* __restrict__ out, int N) {
    int i = blockIdx.x * blockDim.x + threadIdx.x;
    if (i < N) {
        float c = 0.f;
#pragma unroll
        for (int j = 0; j < HID; ++j) c += b_conv[j] * W_fc[j];
        float deg = 1.0f + (float)cnt[i];
        float di = rsqrtf(deg);
        float s = sv[i];
        dinv[i] = di; tval[i] = s * di;
        out[i] = s / deg + c + b_fc[0];
    }
}
__global__ void fb_scatter(const int* __restrict__ src, const int* __restrict__ dst,
                           const float* __restrict__ tval, const float* __restrict__ dinv,
                           float* __restrict__ out, int E) {
    int stride = gridDim.x * blockDim.x;
    for (int e = blockIdx.x * blockDim.x + threadIdx.x; e < E; e += stride) {
        int si = src[e], di = dst[e];
        atomicAdd(&out[di], tval[si] * dinv[di]);
    }
}

extern "C" void kernel_launch(void* const* d_in, const int* in_sizes, int n_in,
                              void* d_out, int out_size, void* d_ws, size_t ws_size,
                              hipStream_t stream) {
    const float* x      = (const float*)d_in[0];
    const int*   ei     = (const int*)d_in[1];
    const float* Wm     = (const float*)d_in[2];
    const float* b_conv = (const float*)d_in[3];
    const float* W_fc   = (const float*)d_in[4];
    const float* b_fc   = (const float*)d_in[5];
    float* out = (float*)d_out;

    const int N = in_sizes[0] / DF;   // 100000
    const int E = in_sizes[1] / 2;    // 3200000
    const int* src = ei;
    const int* dst = ei + E;

    const int P   = (N + 255) >> PBITS;                 // 391
    const int Epw = (((E + WB - 1) / WB) + 3) & ~3;     // 6252 (16B-aligned slices)
    const unsigned avg = (unsigned)((E + P - 1) / P);
    const unsigned cap = ((4u * avg) + 4095u) & ~4095u; // ~36864: 4x avg, 16B-aligned

    char* ws = (char*)d_ws;
    float* sv   = (float*)ws;                               // N
    float* dinv = sv + N;                                   // N
    float* tval = dinv + N;                                 // N
    unsigned* cntS     = (unsigned*)(tval + N);             // WB*PPAD
    unsigned* rowTotal = cntS + (size_t)WB * PPAD;          // 512
    unsigned* sorted   = rowTotal + 512;                    // P*cap

    const size_t need = ((size_t)3 * N + (size_t)WB * PPAD + 512 + (size_t)P * cap) * 4;

    if (P >= 1 && P <= PMAX && N <= (1 << 23) && ws_size >= need) {
        hist_sval_kernel<<<WB, 512, 0, stream>>>(x, dst, Wm, W_fc, cntS, sv, N, E, P, Epw);
        rowscan_kernel<<<P, WB, 0, stream>>>(cntS, rowTotal, cap);
        binscatter_kernel<<<WB, 512, 0, stream>>>(src, dst, cntS, sorted, P, E, Epw);
        degfin_kernel<<<P, 1024, 0, stream>>>(sorted, rowTotal, sv, dinv, tval, N, cap);
        reduce_kernel<<<P, 1024, 0, stream>>>(sorted, rowTotal, tval, dinv,
                                              b_conv, W_fc, b_fc, out, N, cap);
    } else {
        unsigned* fcnt = (unsigned*)(tval + N);
        hipMemsetAsync(fcnt, 0, (size_t)N * 4, stream);
        fb_sval<<<2048, 256, 0, stream>>>(x, Wm, W_fc, sv, N);
        fb_count<<<2048, 256, 0, stream>>>(dst, fcnt, E);
        fb_node<<<(N + 255) / 256, 256, 0, stream>>>(fcnt, sv, b_conv, W_fc, b_fc, dinv, tval, out, N);
        fb_scatter<<<2048, 256, 0, stream>>>(src, dst, tval, dinv, out, E);
    }
}